// Round 2
// baseline (430.306 us; speedup 1.0000x reference)
//
#include <hip/hip_runtime.h>

typedef float  floatx4 __attribute__((ext_vector_type(4)));
typedef float  float4a __attribute__((ext_vector_type(4), aligned(4)));
typedef short  short8  __attribute__((ext_vector_type(8)));
typedef short  short4v __attribute__((ext_vector_type(4)));
typedef int    intx4   __attribute__((ext_vector_type(4)));

#define NB   32
#define NC   512
#define NHW  3136

template<int N> struct IC { static constexpr int value = N; };

// resample map: p//7*6 + min(p%7,5)
__device__ __forceinline__ int ridx(int p) {
    int q = p / 7;
    int r = p - q * 7;
    return q * 6 + (r < 5 ? r : 5);
}
__device__ __forceinline__ short f2bf(float f) {
    unsigned int x = __builtin_bit_cast(unsigned int, f);
    x += 0x7fffu + ((x >> 16) & 1u);           // RNE
    return (short)(x >> 16);
}
__device__ __forceinline__ void gload_lds16(const void* g, void* l) {
    __builtin_amdgcn_global_load_lds(
        (const __attribute__((address_space(1))) unsigned int*)g,
        (__attribute__((address_space(3))) unsigned int*)l, 16, 0, 0);
}

// ---- pre-pass: conv_w f32 -> bf16 with BN scale FOLDED IN (sc>0 since gamma>0);
//      pbg[c] = beta/sc - mean, so h = relu(x + t) and W' = W*sc ----
__global__ __launch_bounds__(256)
void prep_kernel(const float* __restrict__ w,
                 const float* __restrict__ g_, const float* __restrict__ be_,
                 const float* __restrict__ mn_, const float* __restrict__ vr_,
                 short* __restrict__ wb, float* __restrict__ pbg)
{
    int id = (blockIdx.x * 256 + threadIdx.x) * 4;   // 256 blocks x 256 thr x 4 = 262144
    int c  = id & 1023;                              // channel of these 4 elements
    float4a v  = *(const float4a*)(w + id);
    float4a gg = *(const float4a*)(g_ + c);
    float4a vr = *(const float4a*)(vr_ + c);
    short4v s;
#pragma unroll
    for (int j = 0; j < 4; ++j) {
        float sc = gg[j] * rsqrtf(vr[j] + 1e-5f);
        s[j] = f2bf(v[j] * sc);
    }
    *(short4v*)(wb + id) = s;
    if (blockIdx.x == 0) {
        for (int cc2 = threadIdx.x; cc2 < 1024; cc2 += 256) {
            float sc = g_[cc2] * rsqrtf(vr_[cc2] + 1e-5f);
            pbg[cc2] = be_[cc2] / sc - mn_[cc2];
        }
    }
}

// Tile: M=128 spatial slots (112 real: rows 2ph,2ph+1), N=128 out-ch, BK=64.
// Pipelined schedule: raw s_barrier with lgkmcnt(0) only (NO vmcnt(0) drain) —
// Wt DMA + depth-2 x prefetch stay in flight across barriers; counted vmcnt(8)
// drains exactly this body's 4 Wt-DMA ops (issue order pinned [DMA x4][pf x8]
// by sched_barrier; vmcnt retires in-order). pbg staged to LDS once so the
// transform consumes no VMEM. XCD-chunk swizzle keeps each site's nt-pair on
// one XCD's L2 (FETCH 465->189 MB, R1-verified).
__global__ __launch_bounds__(256, 2)
void fused_bn_conv_pool(const float* __restrict__ x,
                        const float* __restrict__ pbg,
                        const short* __restrict__ wgt,
                        float* __restrict__ out)
{
    __shared__ char smem[65536];
    __shared__ float pbgs[1024];
    short* WtB[2] = { (short*)(smem),         (short*)(smem + 32768) };
    short* AtB[2] = { (short*)(smem + 16384), (short*)(smem + 49152) };
    float* ys = (float*)smem;                  // [32][132] f32 epilogue (overlaps buf0)

    const int t    = threadIdx.x;
    // ---- XCD-aware swizzle: grid 1792 = 8 XCDs x 224 ----
    const int bx0  = blockIdx.x;
    const int bx   = (bx0 & 7) * 224 + (bx0 >> 3);
    const int site = bx >> 1;
    const int nt   = bx & 1;                    // o-half: [nt*128, nt*128+128)
    const int b    = site / 28;
    const int ph   = site - b * 28;

    // ---- staging mapping: thread owns 8 consecutive channels (cc) x 4 m (mg) ----
    const int cc     = t & 7;                   // k-octet within BK
    const int mg     = t >> 3;                  // 0..31
    const int m_base = mg * 4;                  // 0..124
    const bool realm = (m_base < 112);
    const int rr = (m_base >= 56) ? 1 : 0;      // row within pair
    const int w0 = m_base - rr * 56;
    const int hs = 4 + ridx(2 * ph + rr);       // gather source row
    const int c0 = ridx(w0);                    // gather base col
    const int offg = hs * 56 + 4 + c0;
    int d_[4];
#pragma unroll
    for (int j = 0; j < 4; ++j) d_[j] = ridx(w0 + j) - c0;   // 0..3
    const int xb   = b * NC * NHW;
    const int offd = 112 * ph + m_base;         // h*56+w == 112*ph+m (linear!)

    // ---- MFMA mapping ----
    const int lid = t & 63;
    const int wv  = t >> 6;
    const int wo  = wv & 1;
    const int wm  = wv >> 1;
    const int col = lid & 15;
    const int q4  = lid >> 4;
    const int obw = wo * 64;
    const int mbw = wm * 64;
    const int sw  = col & 7;                    // read-side chunk swizzle key

    floatx4 acc[4][4];
#pragma unroll
    for (int i = 0; i < 4; ++i)
#pragma unroll
        for (int j = 0; j < 4; ++j)
            acc[i][j] = (floatx4){0.f, 0.f, 0.f, 0.f};

    const short* wrow = wgt + nt * 128 * 1024;

    // ---- stage folded-BN shift to LDS (removes all VMEM from the transform) ----
    *(float4a*)(pbgs + t * 4) = *(const float4a*)(pbg + t * 4);
    __syncthreads();   // full drain once; clean vmcnt slate for the counted waits

    // ---- depth-2 prefetch registers: pf[set][8 channels] of raw x f32 ----
    float4a pf[2][8];

    auto load_into = [&](int kc, auto ic) {
        constexpr int S = decltype(ic)::value;
        if (!realm) return;                     // every wave has >=1 realm lane
        const int k0 = kc * 64;
        const int cb = k0 + cc * 8;
        if (k0 < 512) {
#pragma unroll
            for (int i = 0; i < 8; ++i)
                pf[S][i] = *(const float4a*)(x + xb + (cb + i) * NHW + offd);
        } else {
#pragma unroll
            for (int i = 0; i < 8; ++i)
                pf[S][i] = *(const float4a*)(x + xb + (cb + i - 512) * NHW + offg);
        }
    };

    auto issue_wt = [&](int kcn, short* WtDst) {
        const int k0n = kcn * 64;
#pragma unroll
        for (int it = 0; it < 4; ++it) {
            int q = it * 256 + t;
            int o = q >> 3, sl = q & 7;
            gload_lds16(wrow + o * 1024 + k0n + ((sl ^ (o & 7)) * 8), WtDst + q * 8);
        }
    };

    auto body = [&](int kc, short* Wt, short* WtNext, short* At, auto ic, auto lastc) {
        constexpr int S    = decltype(ic)::value;
        constexpr int LAST = decltype(lastc)::value;
        const int k0 = kc * 64;
        const int cb = k0 + cc * 8;

        // ---- transform pf[S] -> bf16 At[m][k]: relu(x + t[c]), packed-RNE cvt ----
        {
            const bool upper = (k0 >= 512);
            intx4 vj[4];
#pragma unroll
            for (int j = 0; j < 4; ++j) vj[j] = (intx4){0, 0, 0, 0};
            if (realm) {
                float4a tLo = *(const float4a*)(pbgs + cb);       // ds_read, lgkm only
                float4a tHi = *(const float4a*)(pbgs + cb + 4);
                float rprev[4];
#pragma unroll
                for (int i = 0; i < 8; ++i) {
                    const float tch = (i < 4) ? tLo[i] : tHi[i - 4];
                    float vv[4];
                    if (!upper) {
#pragma unroll
                        for (int j = 0; j < 4; ++j) vv[j] = pf[S][i][j];
                    } else {
#pragma unroll
                        for (int j = 0; j < 4; ++j) {
                            int dd = d_[j];
                            float a  = (dd >= 2) ? pf[S][i][2] : pf[S][i][0];
                            float bq = (dd >= 2) ? pf[S][i][3] : pf[S][i][1];
                            vv[j] = (dd & 1) ? bq : a;
                        }
                    }
                    if (!(i & 1)) {
#pragma unroll
                        for (int j = 0; j < 4; ++j) rprev[j] = fmaxf(vv[j] + tch, 0.f);
                    } else {
#pragma unroll
                        for (int j = 0; j < 4; ++j) {
                            float rc = fmaxf(vv[j] + tch, 0.f);
                            unsigned pk;
                            asm("v_cvt_pk_bf16_f32 %0, %1, %2"
                                : "=v"(pk) : "v"(rprev[j]), "v"(rc));
                            vj[j][i >> 1] = (int)pk;
                        }
                    }
                }
            }
#pragma unroll
            for (int j = 0; j < 4; ++j) {
                int m = m_base + j;
                *(intx4*)(At + m * 64 + ((cc ^ (m & 7)) * 8)) = vj[j];
            }
        }

        // ---- publish: drain own Wt-DMA (oldest 4 of <=12 in flight) + LDS ops.
        //      pf(kc+1) x8 stay in flight across the barrier (counted wait). ----
        if (LAST) { asm volatile("s_waitcnt vmcnt(0)" ::: "memory"); }
        else      { asm volatile("s_waitcnt vmcnt(8)" ::: "memory"); }
        asm volatile("s_waitcnt lgkmcnt(0)" ::: "memory");
        __builtin_amdgcn_sched_barrier(0);
        __builtin_amdgcn_s_barrier();
        __builtin_amdgcn_sched_barrier(0);

        // ---- issue next Wt DMA, then x prefetch (order pinned for vmcnt count) ----
        if (kc < 15) issue_wt(kc + 1, WtNext);
        __builtin_amdgcn_sched_barrier(0);
        if (kc < 14) load_into(kc + 2, ic);

        // ---- MFMA: D[o][m] += Wt * At ----
        __builtin_amdgcn_s_setprio(1);
#pragma unroll
        for (int ks = 0; ks < 2; ++ks) {
            const int cb2 = ks * 4 + q4;
            short8 af[4], bf[4];
#pragma unroll
            for (int of = 0; of < 4; ++of) {
                int row = obw + of * 16 + col;
                af[of] = *(const short8*)(Wt + row * 64 + ((cb2 ^ sw) * 8));
            }
#pragma unroll
            for (int mf = 0; mf < 4; ++mf) {
                int row = mbw + mf * 16 + col;
                bf[mf] = *(const short8*)(At + row * 64 + ((cb2 ^ sw) * 8));
            }
#pragma unroll
            for (int of = 0; of < 4; ++of)
#pragma unroll
                for (int mf = 0; mf < 4; ++mf)
                    acc[of][mf] = __builtin_amdgcn_mfma_f32_16x16x32_bf16(
                        af[of], bf[mf], acc[of][mf], 0, 0, 0);
        }
        __builtin_amdgcn_s_setprio(0);
        // no second barrier: double-buffered; next body's lgkm(0)+barrier covers reuse
    };

    // ---- prologue: Wt(0) DMA, then pf(0), pf(1) — order pinned ----
    issue_wt(0, WtB[0]);
    __builtin_amdgcn_sched_barrier(0);
    load_into(0, IC<0>{});
    load_into(1, IC<1>{});

    for (int kc2 = 0; kc2 < 14; kc2 += 2) {
        body(kc2,     WtB[0], WtB[1], AtB[0], IC<0>{}, IC<0>{});
        body(kc2 + 1, WtB[1], WtB[0], AtB[1], IC<1>{}, IC<0>{});
    }
    body(14, WtB[0], WtB[1], AtB[0], IC<0>{}, IC<0>{});
    body(15, WtB[1], WtB[0], AtB[1], IC<1>{}, IC<1>{});

    __syncthreads();   // full drain; all MFMA ds_reads done before ys (overlaps buf0)

    // ---- epilogue: 4 slices of 32 o; acc -> LDS f32 -> 2x2 pool -> f32 out ----
#pragma unroll
    for (int s = 0; s < 4; ++s) {
        if (wo == (s >> 1)) {
#pragma unroll
            for (int of2 = 0; of2 < 2; ++of2) {
                const int of  = (s & 1) * 2 + of2;
                const int olb = of2 * 16 + q4 * 4;   // o within slice (row = q*4+reg)
#pragma unroll
                for (int mf = 0; mf < 4; ++mf) {
                    const int m = mbw + mf * 16 + col;
#pragma unroll
                    for (int rg = 0; rg < 4; ++rg)
                        ys[(olb + rg) * 132 + m] = acc[of][mf][rg];
                }
            }
        }
        __syncthreads();
        for (int i = t; i < 896; i += 256) {
            int ol = i / 28;
            int pw = i - ol * 28;
            const float* yr = ys + ol * 132 + 2 * pw;
            float v = (yr[0] + yr[1] + yr[56] + yr[57]) * 0.25f;
            int og = nt * 128 + s * 32 + ol;
            out[((b * 256 + og) * 28 + ph) * 28 + pw] = v;
        }
        __syncthreads();
    }
}

extern "C" void kernel_launch(void* const* d_in, const int* in_sizes, int n_in,
                              void* d_out, int out_size, void* d_ws, size_t ws_size,
                              hipStream_t stream) {
    (void)in_sizes; (void)n_in; (void)out_size; (void)ws_size;
    const float* x  = (const float*)d_in[0];
    const float* g  = (const float*)d_in[1];
    const float* be = (const float*)d_in[2];
    const float* mn = (const float*)d_in[3];
    const float* vr = (const float*)d_in[4];
    const float* w  = (const float*)d_in[5];
    float* o   = (float*)d_out;
    short* wb  = (short*)d_ws;                        // 512 KB bf16 folded weights
    float* pbg = (float*)((char*)d_ws + 524288);      // 4 KB folded BN shift

    prep_kernel<<<dim3(256), dim3(256), 0, stream>>>(w, g, be, mn, vr, wb, pbg);
    fused_bn_conv_pool<<<dim3(32 * 28 * 2), dim3(256), 0, stream>>>(x, pbg, wb, o);
}

// Round 4
// 344.262 us; speedup vs baseline: 1.2499x; 1.2499x over previous
//
#include <hip/hip_runtime.h>

typedef float  floatx4 __attribute__((ext_vector_type(4)));
typedef float  float4a __attribute__((ext_vector_type(4), aligned(4)));
typedef float  float2a __attribute__((ext_vector_type(2), aligned(8)));
typedef short  short8  __attribute__((ext_vector_type(8)));
typedef short  short4v __attribute__((ext_vector_type(4)));
typedef int    intx4   __attribute__((ext_vector_type(4)));

#define NB   32
#define NC   512
#define NHW  3136

template<int N> struct IC { static constexpr int value = N; };

// resample map: p//7*6 + min(p%7,5)
__device__ __forceinline__ int ridx(int p) {
    int q = p / 7;
    int r = p - q * 7;
    return q * 6 + (r < 5 ? r : 5);
}
__device__ __forceinline__ short f2bf(float f) {
    unsigned int x = __builtin_bit_cast(unsigned int, f);
    x += 0x7fffu + ((x >> 16) & 1u);           // RNE
    return (short)(x >> 16);
}
__device__ __forceinline__ void gload_lds16(const void* g, void* l) {
    __builtin_amdgcn_global_load_lds(
        (const __attribute__((address_space(1))) unsigned int*)g,
        (__attribute__((address_space(3))) unsigned int*)l, 16, 0, 0);
}

// ---- pre-pass: conv_w f32 -> bf16 with BN scale FOLDED IN (sc>0 since gamma>0);
//      pbg[c] = beta/sc - mean, so h = relu(x + t) and W' = W*sc ----
__global__ __launch_bounds__(256)
void prep_kernel(const float* __restrict__ w,
                 const float* __restrict__ g_, const float* __restrict__ be_,
                 const float* __restrict__ mn_, const float* __restrict__ vr_,
                 short* __restrict__ wb, float* __restrict__ pbg)
{
    int id = (blockIdx.x * 256 + threadIdx.x) * 4;   // 256 blocks x 256 thr x 4 = 262144
    int c  = id & 1023;                              // channel of these 4 elements
    float4a v  = *(const float4a*)(w + id);
    float4a gg = *(const float4a*)(g_ + c);
    float4a vr = *(const float4a*)(vr_ + c);
    short4v s;
#pragma unroll
    for (int j = 0; j < 4; ++j) {
        float sc = gg[j] * rsqrtf(vr[j] + 1e-5f);
        s[j] = f2bf(v[j] * sc);
    }
    *(short4v*)(wb + id) = s;
    if (blockIdx.x == 0) {
        for (int cc2 = threadIdx.x; cc2 < 1024; cc2 += 256) {
            float sc = g_[cc2] * rsqrtf(vr_[cc2] + 1e-5f);
            pbg[cc2] = be_[cc2] / sc - mn_[cc2];
        }
    }
}

// ================= NEW PATH: pool commutes with 1x1 conv =================
// y = W·pool(relu(bn(cat))): prepool materializes hp[co][25088 m][8ch] bf16,
// then a pure DMA+MFMA GEMM (no per-body transform, no VALU in the K-loop).

// prepool: block = (b, ph); 448 thr = 16 c-octet groups x 28 pw; 4 iters cover
// 64 lower octets (each lane emits lower AND upper branch for its 8 channels).
__global__ __launch_bounds__(448)
void prepool_kernel(const float* __restrict__ x,
                    const float* __restrict__ pbg,
                    short* __restrict__ hp)       // [128 co][25088 m][8]
{
    __shared__ float pbgs[1024];
    const int t = threadIdx.x;
    if (t < 256) *(float4a*)(pbgs + t * 4) = *(const float4a*)(pbg + t * 4);
    __syncthreads();

    // XCD swizzle: 896 = 8 x 112 (b-contiguous chunks share gather-row overlap in L2)
    const int bx0 = blockIdx.x;
    const int bx  = (bx0 & 7) * 112 + (bx0 >> 3);
    const int b   = bx / 28;
    const int ph  = bx - b * 28;

    const int pw  = t % 28;
    const int cog = t / 28;                        // 0..15

    const int r0 = 2 * ph, r1 = 2 * ph + 1;
    const int g0 = 4 + ridx(2 * ph);
    const int g1 = 4 + ridx(2 * ph + 1);
    const int cw0 = 4 + ridx(2 * pw);
    const int d   = (4 + ridx(2 * pw + 1)) - cw0;  // 0 or 1
    const int ew  = cw0 & ~1;                      // 8B-aligned float2 window
    const int q0  = cw0 & 1;

    const int m     = b * 784 + ph * 28 + pw;
    const int xbase = b * NC * NHW;

#pragma unroll
    for (int it = 0; it < 4; ++it) {
        const int co = it * 16 + cog;              // 0..63 (lower octet index)
        float la[8], ua[8];
#pragma unroll
        for (int i = 0; i < 8; ++i) {
            const float* xc = x + xbase + (co * 8 + i) * NHW;
            float2a l0 = *(const float2a*)(xc + r0 * 56 + 2 * pw);
            float2a l1 = *(const float2a*)(xc + r1 * 56 + 2 * pw);
            float2a a0 = *(const float2a*)(xc + g0 * 56 + ew);
            float2a b0 = *(const float2a*)(xc + g0 * 56 + ew + 2);
            float2a a1 = *(const float2a*)(xc + g1 * 56 + ew);
            float2a b1 = *(const float2a*)(xc + g1 * 56 + ew + 2);
            float tl = pbgs[co * 8 + i];
            float tu = pbgs[512 + co * 8 + i];
            la[i] = 0.25f * (fmaxf(l0[0] + tl, 0.f) + fmaxf(l0[1] + tl, 0.f)
                           + fmaxf(l1[0] + tl, 0.f) + fmaxf(l1[1] + tl, 0.f));
            float u00 = q0 ? a0[1] : a0[0];
            float u10 = q0 ? a1[1] : a1[0];
            int   i1  = q0 + d;                    // 0..2
            float u01 = (i1 == 2) ? b0[0] : (i1 ? a0[1] : a0[0]);
            float u11 = (i1 == 2) ? b1[0] : (i1 ? a1[1] : a1[0]);
            ua[i] = 0.25f * (fmaxf(u00 + tu, 0.f) + fmaxf(u01 + tu, 0.f)
                           + fmaxf(u10 + tu, 0.f) + fmaxf(u11 + tu, 0.f));
        }
        unsigned pl[4], pu[4];
#pragma unroll
        for (int j = 0; j < 4; ++j) {
            asm("v_cvt_pk_bf16_f32 %0, %1, %2" : "=v"(pl[j]) : "v"(la[2*j]), "v"(la[2*j+1]));
            asm("v_cvt_pk_bf16_f32 %0, %1, %2" : "=v"(pu[j]) : "v"(ua[2*j]), "v"(ua[2*j+1]));
        }
        *(intx4*)(hp + (co * 25088 + m) * 8) =
            (intx4){(int)pl[0], (int)pl[1], (int)pl[2], (int)pl[3]};
        *(intx4*)(hp + ((64 + co) * 25088 + m) * 8) =
            (intx4){(int)pu[0], (int)pu[1], (int)pu[2], (int)pu[3]};
    }
}

// gemm: C[25088,256] = hp[25088,1024] x W^T. Tiles 128m x 128o, BK=64, dbuf,
// both tiles via global_load_lds (src XOR-swizzled), 1 barrier/body, no VALU
// transform, direct f32 stores. LDS buffers addressed by parity arithmetic
// (NO pointer arrays — runtime-indexed addrspacecast arrays don't compile).
__global__ __launch_bounds__(256, 2)
void gemm_kernel(const short* __restrict__ hp,
                 const short* __restrict__ wgt,
                 float* __restrict__ out)
{
    __shared__ char smem[65536];

    const int t   = threadIdx.x;
    // XCD swizzle: 392 = 8 x 49; nt-pairs adjacent -> same XCD L2 shares hp tile
    const int bx0 = blockIdx.x;
    const int bx  = (bx0 & 7) * 49 + (bx0 >> 3);
    const int mt  = bx >> 1;
    const int nt  = bx & 1;

    const int lid = t & 63;
    const int wv  = t >> 6;
    const int wo  = wv & 1;
    const int wm  = wv >> 1;
    const int col = lid & 15;
    const int q4  = lid >> 4;
    const int obw = wo * 64;
    const int mbw = wm * 64;
    const int sw  = col & 7;

    const short* wrow = wgt + nt * 128 * 1024;

    floatx4 acc[4][4];
#pragma unroll
    for (int i = 0; i < 4; ++i)
#pragma unroll
        for (int j = 0; j < 4; ++j)
            acc[i][j] = (floatx4){0.f, 0.f, 0.f, 0.f};

    auto issue = [&](int kc) {
        const int k0  = kc * 64;
        short* Wt = (short*)(smem + (kc & 1) * 32768);
        short* At = (short*)(smem + 16384 + (kc & 1) * 32768);
#pragma unroll
        for (int it = 0; it < 4; ++it) {
            int q = it * 256 + t;
            int o = q >> 3, sl = q & 7;
            gload_lds16(wrow + o * 1024 + k0 + ((sl ^ (o & 7)) * 8), Wt + q * 8);
        }
#pragma unroll
        for (int it = 0; it < 4; ++it) {
            int q = it * 256 + t;
            int m = q >> 3, sl = q & 7;
            int cog = (k0 >> 3) + (sl ^ (m & 7));
            gload_lds16(hp + (cog * 25088 + (mt * 128 + m)) * 8, At + q * 8);
        }
    };

    issue(0);

    for (int kc = 0; kc < 16; ++kc) {
        // DMA(kc) was issued one body ago (or prologue) -> mostly retired
        asm volatile("s_waitcnt vmcnt(0)" ::: "memory");
        __builtin_amdgcn_sched_barrier(0);
        __builtin_amdgcn_s_barrier();
        __builtin_amdgcn_sched_barrier(0);
        // safe: all waves past barrier => their MFMA(kc-1) ds_reads retired
        if (kc < 15) issue(kc + 1);
        __builtin_amdgcn_sched_barrier(0);

        short* Wt = (short*)(smem + (kc & 1) * 32768);
        short* At = (short*)(smem + 16384 + (kc & 1) * 32768);
        __builtin_amdgcn_s_setprio(1);
#pragma unroll
        for (int ks = 0; ks < 2; ++ks) {
            const int cb2 = ks * 4 + q4;
            short8 af[4], bf[4];
#pragma unroll
            for (int of = 0; of < 4; ++of) {
                int row = obw + of * 16 + col;
                af[of] = *(const short8*)(Wt + row * 64 + ((cb2 ^ sw) * 8));
            }
#pragma unroll
            for (int mf = 0; mf < 4; ++mf) {
                int row = mbw + mf * 16 + col;
                bf[mf] = *(const short8*)(At + row * 64 + ((cb2 ^ sw) * 8));
            }
#pragma unroll
            for (int of = 0; of < 4; ++of)
#pragma unroll
                for (int mf = 0; mf < 4; ++mf)
                    acc[of][mf] = __builtin_amdgcn_mfma_f32_16x16x32_bf16(
                        af[of], bf[mf], acc[of][mf], 0, 0, 0);
        }
        __builtin_amdgcn_s_setprio(0);
    }

    // epilogue: direct stores; C row o = obw+of*16+q4*4+rg, col m = mbw+mf*16+col
#pragma unroll
    for (int mf = 0; mf < 4; ++mf) {
        const int m_g = mt * 128 + mbw + mf * 16 + col;
        const int bo  = m_g / 784;
        const int r   = m_g - bo * 784;
#pragma unroll
        for (int of = 0; of < 4; ++of) {
            const int o0 = nt * 128 + obw + of * 16 + q4 * 4;
#pragma unroll
            for (int rg = 0; rg < 4; ++rg)
                out[(bo * 256 + o0 + rg) * 784 + r] = acc[of][mf][rg];
        }
    }
}

// ================= FALLBACK PATH (R2 fused kernel, verified) =================
__global__ __launch_bounds__(256, 2)
void fused_bn_conv_pool(const float* __restrict__ x,
                        const float* __restrict__ pbg,
                        const short* __restrict__ wgt,
                        float* __restrict__ out)
{
    __shared__ char smem[65536];
    __shared__ float pbgs[1024];
    short* WtB[2] = { (short*)(smem),         (short*)(smem + 32768) };
    short* AtB[2] = { (short*)(smem + 16384), (short*)(smem + 49152) };
    float* ys = (float*)smem;

    const int t    = threadIdx.x;
    const int bx0  = blockIdx.x;
    const int bx   = (bx0 & 7) * 224 + (bx0 >> 3);
    const int site = bx >> 1;
    const int nt   = bx & 1;
    const int b    = site / 28;
    const int ph   = site - b * 28;

    const int cc     = t & 7;
    const int mg     = t >> 3;
    const int m_base = mg * 4;
    const bool realm = (m_base < 112);
    const int rr = (m_base >= 56) ? 1 : 0;
    const int w0 = m_base - rr * 56;
    const int hs = 4 + ridx(2 * ph + rr);
    const int c0 = ridx(w0);
    const int offg = hs * 56 + 4 + c0;
    int d_[4];
#pragma unroll
    for (int j = 0; j < 4; ++j) d_[j] = ridx(w0 + j) - c0;
    const int xb   = b * NC * NHW;
    const int offd = 112 * ph + m_base;

    const int lid = t & 63;
    const int wv  = t >> 6;
    const int wo  = wv & 1;
    const int wm  = wv >> 1;
    const int col = lid & 15;
    const int q4  = lid >> 4;
    const int obw = wo * 64;
    const int mbw = wm * 64;
    const int sw  = col & 7;

    floatx4 acc[4][4];
#pragma unroll
    for (int i = 0; i < 4; ++i)
#pragma unroll
        for (int j = 0; j < 4; ++j)
            acc[i][j] = (floatx4){0.f, 0.f, 0.f, 0.f};

    const short* wrow = wgt + nt * 128 * 1024;

    *(float4a*)(pbgs + t * 4) = *(const float4a*)(pbg + t * 4);
    __syncthreads();

    float4a pf[2][8];

    auto load_into = [&](int kc, auto ic) {
        constexpr int S = decltype(ic)::value;
        if (!realm) return;
        const int k0 = kc * 64;
        const int cb = k0 + cc * 8;
        if (k0 < 512) {
#pragma unroll
            for (int i = 0; i < 8; ++i)
                pf[S][i] = *(const float4a*)(x + xb + (cb + i) * NHW + offd);
        } else {
#pragma unroll
            for (int i = 0; i < 8; ++i)
                pf[S][i] = *(const float4a*)(x + xb + (cb + i - 512) * NHW + offg);
        }
    };

    auto issue_wt = [&](int kcn, short* WtDst) {
        const int k0n = kcn * 64;
#pragma unroll
        for (int it = 0; it < 4; ++it) {
            int q = it * 256 + t;
            int o = q >> 3, sl = q & 7;
            gload_lds16(wrow + o * 1024 + k0n + ((sl ^ (o & 7)) * 8), WtDst + q * 8);
        }
    };

    auto body = [&](int kc, short* Wt, short* WtNext, short* At, auto ic, auto lastc) {
        constexpr int S    = decltype(ic)::value;
        constexpr int LAST = decltype(lastc)::value;
        const int k0 = kc * 64;
        const int cb = k0 + cc * 8;
        {
            const bool upper = (k0 >= 512);
            intx4 vj[4];
#pragma unroll
            for (int j = 0; j < 4; ++j) vj[j] = (intx4){0, 0, 0, 0};
            if (realm) {
                float4a tLo = *(const float4a*)(pbgs + cb);
                float4a tHi = *(const float4a*)(pbgs + cb + 4);
                float rprev[4];
#pragma unroll
                for (int i = 0; i < 8; ++i) {
                    const float tch = (i < 4) ? tLo[i] : tHi[i - 4];
                    float vv[4];
                    if (!upper) {
#pragma unroll
                        for (int j = 0; j < 4; ++j) vv[j] = pf[S][i][j];
                    } else {
#pragma unroll
                        for (int j = 0; j < 4; ++j) {
                            int dd = d_[j];
                            float a  = (dd >= 2) ? pf[S][i][2] : pf[S][i][0];
                            float bq = (dd >= 2) ? pf[S][i][3] : pf[S][i][1];
                            vv[j] = (dd & 1) ? bq : a;
                        }
                    }
                    if (!(i & 1)) {
#pragma unroll
                        for (int j = 0; j < 4; ++j) rprev[j] = fmaxf(vv[j] + tch, 0.f);
                    } else {
#pragma unroll
                        for (int j = 0; j < 4; ++j) {
                            float rc = fmaxf(vv[j] + tch, 0.f);
                            unsigned pk;
                            asm("v_cvt_pk_bf16_f32 %0, %1, %2"
                                : "=v"(pk) : "v"(rprev[j]), "v"(rc));
                            vj[j][i >> 1] = (int)pk;
                        }
                    }
                }
            }
#pragma unroll
            for (int j = 0; j < 4; ++j) {
                int m = m_base + j;
                *(intx4*)(At + m * 64 + ((cc ^ (m & 7)) * 8)) = vj[j];
            }
        }

        if (LAST) { asm volatile("s_waitcnt vmcnt(0)" ::: "memory"); }
        else      { asm volatile("s_waitcnt vmcnt(8)" ::: "memory"); }
        asm volatile("s_waitcnt lgkmcnt(0)" ::: "memory");
        __builtin_amdgcn_sched_barrier(0);
        __builtin_amdgcn_s_barrier();
        __builtin_amdgcn_sched_barrier(0);

        if (kc < 15) issue_wt(kc + 1, WtNext);
        __builtin_amdgcn_sched_barrier(0);
        if (kc < 14) load_into(kc + 2, ic);

        __builtin_amdgcn_s_setprio(1);
#pragma unroll
        for (int ks = 0; ks < 2; ++ks) {
            const int cb2 = ks * 4 + q4;
            short8 af[4], bf[4];
#pragma unroll
            for (int of = 0; of < 4; ++of) {
                int row = obw + of * 16 + col;
                af[of] = *(const short8*)(Wt + row * 64 + ((cb2 ^ sw) * 8));
            }
#pragma unroll
            for (int mf = 0; mf < 4; ++mf) {
                int row = mbw + mf * 16 + col;
                bf[mf] = *(const short8*)(At + row * 64 + ((cb2 ^ sw) * 8));
            }
#pragma unroll
            for (int of = 0; of < 4; ++of)
#pragma unroll
                for (int mf = 0; mf < 4; ++mf)
                    acc[of][mf] = __builtin_amdgcn_mfma_f32_16x16x32_bf16(
                        af[of], bf[mf], acc[of][mf], 0, 0, 0);
        }
        __builtin_amdgcn_s_setprio(0);
    };

    issue_wt(0, WtB[0]);
    __builtin_amdgcn_sched_barrier(0);
    load_into(0, IC<0>{});
    load_into(1, IC<1>{});

    for (int kc2 = 0; kc2 < 14; kc2 += 2) {
        body(kc2,     WtB[0], WtB[1], AtB[0], IC<0>{}, IC<0>{});
        body(kc2 + 1, WtB[1], WtB[0], AtB[1], IC<1>{}, IC<0>{});
    }
    body(14, WtB[0], WtB[1], AtB[0], IC<0>{}, IC<0>{});
    body(15, WtB[1], WtB[0], AtB[1], IC<1>{}, IC<1>{});

    __syncthreads();

#pragma unroll
    for (int s = 0; s < 4; ++s) {
        if (wo == (s >> 1)) {
#pragma unroll
            for (int of2 = 0; of2 < 2; ++of2) {
                const int of  = (s & 1) * 2 + of2;
                const int olb = of2 * 16 + q4 * 4;
#pragma unroll
                for (int mf = 0; mf < 4; ++mf) {
                    const int m = mbw + mf * 16 + col;
#pragma unroll
                    for (int rg = 0; rg < 4; ++rg)
                        ys[(olb + rg) * 132 + m] = acc[of][mf][rg];
                }
            }
        }
        __syncthreads();
        for (int i = t; i < 896; i += 256) {
            int ol = i / 28;
            int pw = i - ol * 28;
            const float* yr = ys + ol * 132 + 2 * pw;
            float v = (yr[0] + yr[1] + yr[56] + yr[57]) * 0.25f;
            int og = nt * 128 + s * 32 + ol;
            out[((b * 256 + og) * 28 + ph) * 28 + pw] = v;
        }
        __syncthreads();
    }
}

extern "C" void kernel_launch(void* const* d_in, const int* in_sizes, int n_in,
                              void* d_out, int out_size, void* d_ws, size_t ws_size,
                              hipStream_t stream) {
    (void)in_sizes; (void)n_in; (void)out_size;
    const float* x  = (const float*)d_in[0];
    const float* g  = (const float*)d_in[1];
    const float* be = (const float*)d_in[2];
    const float* mn = (const float*)d_in[3];
    const float* vr = (const float*)d_in[4];
    const float* w  = (const float*)d_in[5];
    float* o   = (float*)d_out;

    const size_t HP_BYTES = 128u * 25088u * 8u * 2u;       // 51,380,224
    const size_t WB_BYTES = 524288;
    const size_t NEED     = HP_BYTES + WB_BYTES + 4096;    // 51,908,608

    if (ws_size >= NEED) {
        short* hp  = (short*)d_ws;
        short* wb  = (short*)((char*)d_ws + HP_BYTES);
        float* pbg = (float*)((char*)d_ws + HP_BYTES + WB_BYTES);
        prep_kernel<<<dim3(256), dim3(256), 0, stream>>>(w, g, be, mn, vr, wb, pbg);
        prepool_kernel<<<dim3(32 * 28), dim3(448), 0, stream>>>(x, pbg, hp);
        gemm_kernel<<<dim3(196 * 2), dim3(256), 0, stream>>>(hp, wb, o);
    } else {
        short* wb  = (short*)d_ws;
        float* pbg = (float*)((char*)d_ws + WB_BYTES);
        prep_kernel<<<dim3(256), dim3(256), 0, stream>>>(w, g, be, mn, vr, wb, pbg);
        fused_bn_conv_pool<<<dim3(32 * 28 * 2), dim3(256), 0, stream>>>(x, pbg, wb, o);
    }
}